// Round 25
// baseline (113.033 us; speedup 1.0000x reference)
//
#include <hip/hip_runtime.h>
#include <hip/hip_bf16.h>

typedef unsigned short u16;
typedef unsigned u32;
typedef unsigned long long u64;
typedef float f32x4 __attribute__((ext_vector_type(4)));
typedef __bf16 bf16x8 __attribute__((ext_vector_type(8)));

#define NB 2
#define NS 2048
#define ND 1024
#define NH 16
#define HD 64

__device__ inline u16 bfbits(float f) { __bf16 h = (__bf16)f; return __builtin_bit_cast(u16, h); }

__device__ inline void gl16(const u16* g, u16* l) {
  __builtin_amdgcn_global_load_lds((const __attribute__((address_space(1))) void*)(g),
                                   (__attribute__((address_space(3))) void*)(l), 16, 0, 0);
}

// ---------------- fused prep kernel (mask branch lives in gemm_qkv) ----------------
// blocks [0,4096): weight transpose f32->bf16^T (4 weights x 1024 tiles)
// blocks [4096,8192): x f32->bf16 convert
// blocks [8192,8448): rope tables
__global__ void __launch_bounds__(256)
prep_all(const float* __restrict__ W0, const float* __restrict__ W1,
         const float* __restrict__ W2, const float* __restrict__ W3,
         u16* __restrict__ T0, u16* __restrict__ T1, u16* __restrict__ T2, u16* __restrict__ T3,
         const float* __restrict__ x, u16* __restrict__ xb,
         float* __restrict__ cost, float* __restrict__ sint) {
  const int bid = blockIdx.x, t = threadIdx.x;
  if (bid < 4096) {
    __shared__ float tile[32][33];
    const float* Ws[4] = {W0, W1, W2, W3};
    u16* Ts[4] = {T0, T1, T2, T3};
    const float* __restrict__ W = Ws[bid >> 10];
    u16* __restrict__ WT = Ts[bid >> 10];
    const int rem = bid & 1023;
    const int n0 = (rem & 31) * 32, k0 = (rem >> 5) * 32;
    const int tx = t & 31, ty = t >> 5;
#pragma unroll
    for (int i = 0; i < 4; ++i)
      tile[ty + i * 8][tx] = W[(size_t)(k0 + ty + i * 8) * ND + n0 + tx];
    __syncthreads();
#pragma unroll
    for (int i = 0; i < 4; ++i)
      WT[(size_t)(n0 + ty + i * 8) * ND + k0 + tx] = bfbits(tile[tx][ty + i * 8]);
  } else if (bid < 8192) {
    const int i = (bid - 4096) * 256 + t;  // over NB*NS*ND/4
    float4 v = reinterpret_cast<const float4*>(x)[i];
    uint2 pk;
    pk.x = (unsigned)bfbits(v.x) | ((unsigned)bfbits(v.y) << 16);
    pk.y = (unsigned)bfbits(v.z) | ((unsigned)bfbits(v.w) << 16);
    reinterpret_cast<uint2*>(xb)[i] = pk;
  } else {
    const int i = (bid - 8192) * 256 + t;  // NS*32
    const int s = i >> 5, d = i & 31;
    float invf = powf(10000.f, -(float)d / 32.f);
    float a = (float)s * invf;
    cost[i] = cosf(a);
    sint[i] = sinf(a);
  }
}

// ---------------- fused QKV GEMM (v11: 128x256 tiles, BK=64, 3-buffer counted) --------------
// blocks [0,384): GEMM. Tile 128 rows x 256 cols, BK=64, XOR swizzle (conflict-free,
// measured). 3-buffer LDS (A 3x16KB + B 3x32KB = 144KB): the R13/R23-PROVEN protocol
// (gemm_out runs it today): wait-own vmcnt(6) [tile s+1's 6 loads stay in flight] ->
// s_barrier [tile s fully staged by all waves; buf (s+2)%3 free] -> issue tile s+2 ->
// compute tile s. Tile loads get TWO compute phases of latency cover (vs one with the old
// 2-buffer drain). Finer grid (384 blocks) backfills the 64 CUs the 192-block config idled.
// XCD map: xcd = hid&7 owns m-tiles 4*xcd..+3 x all 12 panels (A L2-hot).
// Wave (wm,wn)=2x4: 64 rows x 64 cols (one head), acc[4][4].
// blocks [384,448): closed-form mask builder (bar_ids sorted => vis = G(k) | same-bar
// interval; no ballot loop, no atomics). q pre-scaled by 0.125*log2(e); q/k stored in the
// HD-permuted packed-pair layout.
__global__ void __launch_bounds__(512, 2)
gemm_qkv(const u16* __restrict__ A, const u16* __restrict__ BT3,
         const float* __restrict__ bq, const float* __restrict__ bk, const float* __restrict__ bv,
         u16* __restrict__ qbuf, u16* __restrict__ kbuf, u16* __restrict__ vtbuf,
         const float* __restrict__ cost, const float* __restrict__ sint,
         const int* __restrict__ bar, const int* __restrict__ inst,
         const int* __restrict__ lidx, u64* __restrict__ mb, u32* __restrict__ tilebits) {
  constexpr int K = ND;
  constexpr int NT = K / 64;                    // 16 K-tiles
  __shared__ alignas(16) u16 Alds[3][128][64];  // 48 KB
  __shared__ alignas(16) u16 Blds[3][256][64];  // 96 KB
  const int t = threadIdx.x;
  const int hid = (int)blockIdx.x;              // 0..447

  if (hid >= 384) {
    // ---- closed-form mask tail (R22 logic; scratch aliased into this kernel's LDS) ----
    int* sbar = reinterpret_cast<int*>(&Blds[0][0][0]);   // 16 KB
    int* sinst = sbar + NB * NS;                          // 16 KB
    int* firsts = reinterpret_cast<int*>(&Alds[0][0][0]); // NB*128 ints
    int* lasts = firsts + NB * 128;                       // NB*128 ints
    u64* Gw = reinterpret_cast<u64*>(lasts + NB * 128);   // NB*32 u64
    for (int i = t; i < NB * NS; i += 512) {
      sbar[i] = bar[i];
      sinst[i] = inst[i];
    }
    __syncthreads();
    for (int i = t; i < NB * NS; i += 512) {
      const int idx = i & (NS - 1);
      const int v = sbar[i];
      if (v >= 0 && v < 128) {
        if (idx == 0 || sbar[i - 1] != v) firsts[(i >> 11) * 128 + v] = idx;
        if (idx == NS - 1 || sbar[i + 1] != v) lasts[(i >> 11) * 128 + v] = idx;
      }
    }
    {
      const int w8 = t >> 6, lane = t & 63;
#pragma unroll
      for (int p8 = 0; p8 < 8; ++p8) {
        const int p = w8 * 8 + p8;
        const int gb = p >> 5, gkt = p & 31;
        const int k = gkt * 64 + lane;
        const bool gbit = (sinst[gb * NS + k] == 129) || (sbar[gb * NS + k] == -1);
        const u64 wd = __ballot(gbit);
        if (lane == 0) Gw[p] = wd;
      }
    }
    __syncthreads();
    const bool fc = (lidx[0] < 4);
    const int w8 = t >> 6, lane = t & 63;
    const int gw = (hid - 384) * 8 + w8;        // global wave id 0..511
#pragma unroll
    for (int rr = 0; rr < 8; ++rr) {
      const int pair = gw + 512 * rr;           // 0..4095 (strided: balanced)
      const int b = pair >> 11, q = pair & (NS - 1);
      const int qt = q >> 6;
      const int qb = sbar[b * NS + q];
      const bool qreal = sinst[b * NS + q] < 129;
      int lo = NS, hi = -1;
      if (fc && qreal && qb >= 0 && qb < 128) {
        lo = firsts[b * 128 + qb];
        hi = lasts[b * 128 + qb];
      }
      const int kt = lane;
      if (kt <= qt) {
        u64 word;
        if (!fc) {
          word = ~0ULL;
        } else {
          word = Gw[b * 32 + kt];
          const int base = kt * 64;
          const int s = lo - base, e = hi - base;
          if (e >= 0 && s <= 63) {
            const int cs = s < 0 ? 0 : s;
            const int ce = e > 63 ? 63 : e;
            u64 m = (ce >= 63) ? ~0ULL : ((1ULL << (ce + 1)) - 1);
            if (cs > 0) m &= ~((1ULL << cs) - 1);
            word |= m;
          }
        }
        if (kt == qt) {
          const int qq = q & 63;
          word &= (qq >= 63) ? ~0ULL : ((1ULL << (qq + 1)) - 1);
        }
        mb[(((size_t)b * NS + q) << 5) + kt] = word;
      }
    }
    if (hid == 384 && w8 == 0) {
      const int b = lane >> 5, qt = lane & 31;
      u32 tbw;
      if (!fc) {
        tbw = (qt >= 31) ? 0xFFFFFFFFu : ((1u << (qt + 1)) - 1);
      } else {
        const int v0 = sbar[b * NS + qt * 64];
        const int v1 = sbar[b * NS + qt * 64 + 63];
        const int lo_t = (v0 >= 0 && v0 < 128) ? firsts[b * 128 + v0] : 0;
        const int hi_t = (v1 >= 0 && v1 < 128) ? lasts[b * 128 + v1] : NS - 1;
        tbw = 0;
        for (int kt = 0; kt <= qt; ++kt) {
          const bool on = (kt == qt) || (Gw[b * 32 + kt] != 0ULL) ||
                          (kt * 64 <= hi_t && kt * 64 + 63 >= lo_t);
          if (on) tbw |= (1u << kt);
        }
      }
      if (lane < 64) tilebits[lane] = tbw;
    }
    return;
  }

  // XCD-chunked block map: xcd owns 4 m-tiles x 12 panels (48 blocks/XCD)
  const int xcd = hid & 7, j = hid >> 3;        // j 0..47
  const int m0 = (xcd * 4 + j / 12) << 7;       // 32 m-tiles of 128 rows
  const int nblk = j % 12;
  const int proj = nblk >> 2;                   // 0:q 1:k 2:v
  const int n0 = (nblk & 3) << 8;               // within-proj col base (256-wide)
  const int w = t >> 6, lane = t & 63, lr = lane & 15, lg = lane >> 4;
  const int wm = w >> 2, wn = w & 3;            // 2 x 4 wave grid: 64 rows x 64 cols each
  const float* __restrict__ bias = proj == 0 ? bq : (proj == 1 ? bk : bv);
  f32x4 acc[4][4] = {};

  // staging: A 128 rows -> wave w stages rows w*16..+15 (2 gl16); B 256 rows -> rows
  // w*32..+31 (4 gl16). 6 gl16/thread/K-tile. LDS[row][u] = G[row][u ^ (row&7)] (16B units).
  const int srow = lane >> 3;  // 0..7
  const int lcol = (lane & 7) ^ srow;
  const u16* Ag = A + (size_t)(m0 + w * 16 + srow) * K + lcol * 8;
  const u16* Bg = BT3 + (size_t)(proj * ND + n0 + w * 32 + srow) * K + lcol * 8;
  const int swz = lr & 7;  // read-side XOR (row&7 == lr&7 for all fragment rows)

  // prologue: stage K-tiles 0,1 into bufs 0,1
#pragma unroll
  for (int p = 0; p < 2; ++p) {
#pragma unroll
    for (int c = 0; c < 2; ++c)
      gl16(Ag + p * 64 + (size_t)c * 8 * K, &Alds[p][w * 16 + c * 8][0]);
#pragma unroll
    for (int c = 0; c < 4; ++c)
      gl16(Bg + p * 64 + (size_t)c * 8 * K, &Blds[p][w * 32 + c * 8][0]);
  }

  int cur = 0;
  for (int s = 0; s < NT; ++s) {
    // wait own tile-s loads (tile s+1's 6 stay in flight), THEN barrier
    if (s + 1 < NT) {
      asm volatile("s_waitcnt vmcnt(6)" ::: "memory");
    } else {
      asm volatile("s_waitcnt vmcnt(0)" ::: "memory");
    }
    __builtin_amdgcn_s_barrier();
    if (s + 2 < NT) {  // issue tile s+2 into the buffer freed by this barrier
      int bn = cur + 2;
      if (bn >= 3) bn -= 3;
      const int k0n = (s + 2) * 64;
#pragma unroll
      for (int c = 0; c < 2; ++c)
        gl16(Ag + k0n + (size_t)c * 8 * K, &Alds[bn][w * 16 + c * 8][0]);
#pragma unroll
      for (int c = 0; c < 4; ++c)
        gl16(Bg + k0n + (size_t)c * 8 * K, &Blds[bn][w * 32 + c * 8][0]);
    }
    // B fragments: rows wn*64 + ni*16 + lr; A: rows wm*64 + mi*16 + lr; unit ((ks*4+lg)^swz)
    bf16x8 bfr[4][2];
#pragma unroll
    for (int ni = 0; ni < 4; ++ni)
#pragma unroll
      for (int ks = 0; ks < 2; ++ks)
        bfr[ni][ks] = *reinterpret_cast<const bf16x8*>(
            &Blds[cur][wn * 64 + ni * 16 + lr][(((ks << 2) + lg) ^ swz) << 3]);
#pragma unroll
    for (int mi = 0; mi < 4; ++mi) {
#pragma unroll
      for (int ks = 0; ks < 2; ++ks) {
        const bf16x8 af = *reinterpret_cast<const bf16x8*>(
            &Alds[cur][wm * 64 + mi * 16 + lr][(((ks << 2) + lg) ^ swz) << 3]);
#pragma unroll
        for (int ni = 0; ni < 4; ++ni)
          acc[mi][ni] = __builtin_amdgcn_mfma_f32_16x16x32_bf16(af, bfr[ni][ks], acc[mi][ni], 0, 0, 0);
      }
    }
    cur = (cur == 2) ? 0 : cur + 1;
  }

  if (proj < 2) {
    u16* out = proj ? kbuf : qbuf;
    const float qs = proj == 0 ? 0.18033688f : 1.0f;  // 0.125 * log2(e): exp2-domain scores
    const int colbase = n0 + wn * 64;
    const int h = colbase >> 6;  // wave's 64 cols = one head
#pragma unroll
    for (int mi = 0; mi < 4; ++mi)
#pragma unroll
      for (int r = 0; r < 4; ++r) {
        const int row = m0 + wm * 64 + mi * 16 + lg * 4 + r;
        const int b = row >> 11, s = row & (NS - 1);
        u16* op = out + ((size_t)(b * NH + h) * NS + s) * HD;
#pragma unroll
        for (int nf = 0; nf < 2; ++nf) {
          const int dlo = nf * 16 + lr;  // < 32
          float lo = acc[mi][nf][r] + bias[colbase + dlo];
          float hi = acc[mi][nf + 2][r] + bias[colbase + dlo + 32];
          float c = cost[s * 32 + dlo], si = sint[s * 32 + dlo];
          const u32 pk = (u32)bfbits((lo * c - hi * si) * qs) |
                         ((u32)bfbits((hi * c + lo * si) * qs) << 16);
          *reinterpret_cast<u32*>(op + 2 * dlo) = pk;  // permuted layout: one 4B store
        }
      }
  } else {
    u16* out = vtbuf;
#pragma unroll
    for (int mi = 0; mi < 4; ++mi)
#pragma unroll
      for (int ni = 0; ni < 4; ++ni) {
        const int col = n0 + wn * 64 + ni * 16 + lr;
        const int h = col >> 6, d = col & 63;
        const int s0 = m0 + wm * 64 + mi * 16 + lg * 4;  // 4 consecutive s = r
        const int b = s0 >> 11, s = s0 & (NS - 1);
        uint2 pk;
        pk.x = (unsigned)bfbits(acc[mi][ni][0] + bias[col]) |
               ((unsigned)bfbits(acc[mi][ni][1] + bias[col]) << 16);
        pk.y = (unsigned)bfbits(acc[mi][ni][2] + bias[col]) |
               ((unsigned)bfbits(acc[mi][ni][3] + bias[col]) << 16);
        *reinterpret_cast<uint2*>(out + ((size_t)(b * NH + h) * HD + d) * NS + s) = pk;
      }
  }
}

// ---------------- output GEMM (v3: 128x128 tiles, BK=64, 3-buffer, 256 blocks) --------------
// C = A*B^T + bias, f32 out. 256 blocks x 512 threads = 1 block/CU. Tile 128x128, BK=64 with
// the XOR swizzle, 3-buffer LDS (96KB): wait-own vmcnt(4) -> s_barrier -> issue tile s+2.
// XCD map: each XCD owns one 128-col B panel (L2-resident) and walks the 32 m-tiles.
__global__ void __launch_bounds__(512)
gemm_out(const u16* __restrict__ A, const u16* __restrict__ BT, const float* __restrict__ bias,
         float* __restrict__ out) {
  constexpr int K = ND;
  __shared__ alignas(16) u16 Alds[3][128][64];  // 48 KB
  __shared__ alignas(16) u16 Blds[3][128][64];  // 48 KB
  const int t = threadIdx.x;
  const int hid = (int)blockIdx.x;              // 0..255
  const int n0 = (hid & 7) * 128;               // 8 n-tiles = 8 XCDs (B panel L2-resident)
  const int m0 = (hid >> 3) * 128;              // 32 m-tiles
  const int w = t >> 6, lane = t & 63, lr = lane & 15, lg = lane >> 4;
  const int wm = w >> 1, wn = w & 1;            // 4 x 2 wave grid
  f32x4 acc[2][4] = {};

  const int srow = lane >> 3;  // 0..7
  const int lcol = (lane & 7) ^ srow;
  const u16* Ag = A + (size_t)(m0 + w * 16 + srow) * K + lcol * 8;
  const u16* Bg = BT + (size_t)(n0 + w * 16 + srow) * K + lcol * 8;
  const int swz = lr & 7;

#pragma unroll
  for (int p = 0; p < 2; ++p) {
#pragma unroll
    for (int c = 0; c < 2; ++c) {
      gl16(Ag + p * 64 + (size_t)c * 8 * K, &Alds[p][w * 16 + c * 8][0]);
      gl16(Bg + p * 64 + (size_t)c * 8 * K, &Blds[p][w * 16 + c * 8][0]);
    }
  }

  int cur = 0;
  for (int s = 0; s < K / 64; ++s) {
    if (s + 1 < K / 64) {
      asm volatile("s_waitcnt vmcnt(4)" ::: "memory");
    } else {
      asm volatile("s_waitcnt vmcnt(0)" ::: "memory");
    }
    __builtin_amdgcn_s_barrier();
    if (s + 2 < K / 64) {
      int bn = cur + 2;
      if (bn >= 3) bn -= 3;
      const int k0n = (s + 2) * 64;
#pragma unroll
      for (int c = 0; c < 2; ++c) {
        gl16(Ag + k0n + (size_t)c * 8 * K, &Alds[bn][w * 16 + c * 8][0]);
        gl16(Bg + k0n + (size_t)c * 8 * K, &Blds[bn][w * 16 + c * 8][0]);
      }
    }
    bf16x8 bfr[4][2];
#pragma unroll
    for (int ni = 0; ni < 4; ++ni)
#pragma unroll
      for (int ks = 0; ks < 2; ++ks)
        bfr[ni][ks] = *reinterpret_cast<const bf16x8*>(
            &Blds[cur][wn * 64 + ni * 16 + lr][(((ks << 2) + lg) ^ swz) << 3]);
#pragma unroll
    for (int mi = 0; mi < 2; ++mi) {
#pragma unroll
      for (int ks = 0; ks < 2; ++ks) {
        const bf16x8 af = *reinterpret_cast<const bf16x8*>(
            &Alds[cur][wm * 32 + mi * 16 + lr][(((ks << 2) + lg) ^ swz) << 3]);
#pragma unroll
        for (int ni = 0; ni < 4; ++ni)
          acc[mi][ni] = __builtin_amdgcn_mfma_f32_16x16x32_bf16(af, bfr[ni][ks], acc[mi][ni], 0, 0, 0);
      }
    }
    cur = (cur == 2) ? 0 : cur + 1;
  }

#pragma unroll
  for (int mi = 0; mi < 2; ++mi)
#pragma unroll
    for (int r = 0; r < 4; ++r) {
      const int row = m0 + wm * 32 + mi * 16 + lg * 4 + r;
#pragma unroll
      for (int ni = 0; ni < 4; ++ni) {
        const int col = n0 + wn * 64 + ni * 16 + lr;
        out[(size_t)row * ND + col] = acc[mi][ni][r] + bias[col];
      }
    }
}

// ---------------- fused masked flash attention (v12: tilebits iteration) ----------
// grid 1024 x 4 waves, 64-row q-tiles, LDS 40KB -> 4 blocks/CU (16 waves). __syncthreads dbuf
// (race-free). Per-XCD mapping: xcd = hid&7 hosts 4 (b,h) panels; qt map {31-j, j, 23-j, 8+j}
// keeps the co-resident quad balanced. Iterate only set bits of tilebits[b*32+qt]; within a
// tile, waves whose 16 rows are all masked skip compute. q/k in HD-permuted layout
// (transparent here: Q and K share the permutation).
__global__ void __launch_bounds__(256, 4)
attn_fused(const u16* __restrict__ qb, const u16* __restrict__ kb, const u16* __restrict__ vtb,
           const u64* __restrict__ mb, const u32* __restrict__ tilebits,
           u16* __restrict__ attnout) {
  __shared__ alignas(16) u16 Klds[2][64][64];   // [buf][k][d]  rows 128B, swizzled 16B units
  __shared__ alignas(16) u16 Vlds[2][64][64];   // [buf][d][k]
  __shared__ alignas(16) u16 Plds[4][16][64];   // per-wave P [q][k], swizzled 8B units
  const int t = threadIdx.x, w = t >> 6, lane = t & 63, lr = lane & 15, lg = lane >> 4;
  const int hid = (int)blockIdx.x;              // 0..1023
  const int xcd = hid & 7, ix = hid >> 3;
  const int g = ix >> 5, r0 = ix & 31;
  const int bh = xcd * 4 + (r0 >> 3);
  const int b = bh >> 4, h = bh & 15;
  const int j = r0 & 7;
  const int qt = (g == 0) ? 31 - j : (g == 1) ? j : (g == 2) ? 23 - j : 8 + j;
  const int qbase = qt * 64;
  const u16* __restrict__ qh = qb + (size_t)(b * NH + h) * NS * HD;
  const u16* __restrict__ kh = kb + (size_t)(b * NH + h) * NS * HD;
  const u16* __restrict__ vth = vtb + (size_t)(b * NH + h) * HD * NS;
  const u32 bits = tilebits[b * 32 + qt];       // nonzero: diagonal always visible
  const int nt = __popc(bits);

  const int srow = lane >> 3;  // 0..7
  const int lcol = (lane & 7) ^ srow;
  const int sw = lr & 7;

  const int qrow = qbase + w * 16 + lr;
  const bf16x8 qf0 = *reinterpret_cast<const bf16x8*>(qh + (size_t)qrow * HD + lg * 8);
  const bf16x8 qf1 = *reinterpret_cast<const bf16x8*>(qh + (size_t)qrow * HD + 32 + lg * 8);
  const u64* __restrict__ mrow = mb + (((size_t)b * NS + qrow) << 5);

  float m_s = -1e30f, l_s = 0.f;
  f32x4 oacc[4] = {};
  int cur = 0;

  const int kt0 = __ffs(bits) - 1;
  u32 rem = bits & (bits - 1);
  {
    const int kb0 = kt0 << 6;
#pragma unroll
    for (int c = 0; c < 2; ++c) {
      const int row = w * 16 + c * 8 + srow;
      gl16(kh + (size_t)(kb0 + row) * HD + lcol * 8, &Klds[0][w * 16 + c * 8][0]);
      gl16(vth + (size_t)row * NS + kb0 + lcol * 8, &Vlds[0][w * 16 + c * 8][0]);
    }
  }
  u64 mw = mrow[kt0];

  for (int i = 0; i < nt; ++i) {
    __syncthreads();  // drains vmcnt: buf[cur] staged by ALL waves; buf[cur^1] free
    u64 mwn = 0ULL;
    if (rem) {
      const int ktn = __ffs(rem) - 1;
      rem &= rem - 1;
      const int kb0n = ktn << 6;
#pragma unroll
      for (int c = 0; c < 2; ++c) {
        const int row = w * 16 + c * 8 + srow;
        gl16(kh + (size_t)(kb0n + row) * HD + lcol * 8, &Klds[cur ^ 1][w * 16 + c * 8][0]);
        gl16(vth + (size_t)row * NS + kb0n + lcol * 8, &Vlds[cur ^ 1][w * 16 + c * 8][0]);
      }
      mwn = mrow[ktn];
    }

    if (!__all(mw == 0ULL)) {
      const u16* Kb = &Klds[cur][0][0];
      const u16* Vb = &Vlds[cur][0][0];

      f32x4 sacc[4] = {};
      __builtin_amdgcn_s_setprio(1);
#pragma unroll
      for (int n = 0; n < 4; ++n) {
        const u16* kr = Kb + (n * 16 + lr) * 64;
        bf16x8 kf0 = *reinterpret_cast<const bf16x8*>(kr + ((lg ^ sw) << 3));
        bf16x8 kf1 = *reinterpret_cast<const bf16x8*>(kr + (((4 + lg) ^ sw) << 3));
        sacc[n] = __builtin_amdgcn_mfma_f32_16x16x32_bf16(kf0, qf0, sacc[n], 0, 0, 0);
        sacc[n] = __builtin_amdgcn_mfma_f32_16x16x32_bf16(kf1, qf1, sacc[n], 0, 0, 0);
      }
      __builtin_amdgcn_s_setprio(0);

      float pm[4][4];
      float mx4[4];
#pragma unroll
      for (int n = 0; n < 4; ++n) {
#pragma unroll
        for (int r = 0; r < 4; ++r) {
          const bool vis = (mw >> (n * 16 + lg * 4 + r)) & 1ULL;
          pm[n][r] = vis ? sacc[n][r] : -3e30f;
        }
        mx4[n] = fmaxf(fmaxf(pm[n][0], pm[n][1]), fmaxf(pm[n][2], pm[n][3]));
      }
      float mx = fmaxf(fmaxf(mx4[0], mx4[1]), fmaxf(mx4[2], mx4[3]));
      mx = fmaxf(mx, __shfl_xor(mx, 16));
      mx = fmaxf(mx, __shfl_xor(mx, 32));

      const bool skip = __all(mx <= m_s + 11.5415603f);
      const float mn = skip ? m_s : fmaxf(m_s, mx);

      float rs = 0.f;
#pragma unroll
      for (int n = 0; n < 4; ++n) {
        const float e0 = exp2f(pm[n][0] - mn);
        const float e1 = exp2f(pm[n][1] - mn);
        const float e2 = exp2f(pm[n][2] - mn);
        const float e3 = exp2f(pm[n][3] - mn);
        rs += (e0 + e1) + (e2 + e3);
        uint2 pk;
        pk.x = (unsigned)bfbits(e0) | ((unsigned)bfbits(e1) << 16);
        pk.y = (unsigned)bfbits(e2) | ((unsigned)bfbits(e3) << 16);
        *reinterpret_cast<uint2*>(&Plds[w][lr][(((n << 2) + lg) ^ (lr & 14)) << 2]) = pk;
      }
      rs += __shfl_xor(rs, 16);
      rs += __shfl_xor(rs, 32);

      if (skip) {
        l_s += rs;
      } else {
        const float sf = exp2f(m_s - mn);
        m_s = mn;
        l_s = l_s * sf + rs;
        float sfr[4];
#pragma unroll
        for (int r = 0; r < 4; ++r) sfr[r] = __shfl(sf, lg * 4 + r);
#pragma unroll
        for (int nd = 0; nd < 4; ++nd)
#pragma unroll
          for (int r = 0; r < 4; ++r) oacc[nd][r] *= sfr[r];
      }

      const bf16x8 pf0 = *reinterpret_cast<const bf16x8*>(&Plds[w][lr][((2 * lg) ^ (lr & 14)) << 2]);
      const bf16x8 pf1 = *reinterpret_cast<const bf16x8*>(&Plds[w][lr][((8 + 2 * lg) ^ (lr & 14)) << 2]);
      __builtin_amdgcn_s_setprio(1);
#pragma unroll
      for (int nd = 0; nd < 4; ++nd) {
        const u16* vr = Vb + (nd * 16 + lr) * 64;
        bf16x8 vf0 = *reinterpret_cast<const bf16x8*>(vr + ((lg ^ sw) << 3));
        bf16x8 vf1 = *reinterpret_cast<const bf16x8*>(vr + (((4 + lg) ^ sw) << 3));
        oacc[nd] = __builtin_amdgcn_mfma_f32_16x16x32_bf16(pf0, vf0, oacc[nd], 0, 0, 0);
        oacc[nd] = __builtin_amdgcn_mfma_f32_16x16x32_bf16(pf1, vf1, oacc[nd], 0, 0, 0);
      }
      __builtin_amdgcn_s_setprio(0);
    }

    mw = mwn;
    cur ^= 1;
  }

  float il[4];
#pragma unroll
  for (int r = 0; r < 4; ++r) il[r] = 1.f / __shfl(l_s, lg * 4 + r);
#pragma unroll
  for (int nd = 0; nd < 4; ++nd)
#pragma unroll
    for (int r = 0; r < 4; ++r) {
      const int i = qbase + w * 16 + lg * 4 + r;
      attnout[(size_t)(b * NS + i) * ND + h * HD + nd * 16 + lr] = bfbits(oacc[nd][r] * il[r]);
    }
}

// ---------------- launch ----------------
extern "C" void kernel_launch(void* const* d_in, const int* in_sizes, int n_in,
                              void* d_out, int out_size, void* d_ws, size_t ws_size,
                              hipStream_t stream) {
  const float* x = (const float*)d_in[0];
  const int* bar = (const int*)d_in[1];
  const int* inst = (const int*)d_in[2];
  const int* lidx = (const int*)d_in[3];
  const float* Wq = (const float*)d_in[4];
  const float* bq = (const float*)d_in[5];
  const float* Wk = (const float*)d_in[6];
  const float* bk = (const float*)d_in[7];
  const float* Wv = (const float*)d_in[8];
  const float* bv = (const float*)d_in[9];
  const float* Wo = (const float*)d_in[10];
  const float* bo = (const float*)d_in[11];
  float* out = (float*)d_out;

  char* ws = (char*)d_ws;
  constexpr size_t XB = (size_t)NB * NS * ND * 2;   // 8 MB bf16 token-major buffer
  constexpr size_t WT = (size_t)ND * ND * 2;        // 2 MB
  u16* xb   = (u16*)(ws);
  u16* WqT  = (u16*)(ws + XB);                      // WqT|WkT|WvT contiguous = [3072][1024]
  u16* WkT  = (u16*)(ws + XB + 1 * WT);
  u16* WvT  = (u16*)(ws + XB + 2 * WT);
  u16* WoT  = (u16*)(ws + XB + 3 * WT);
  u16* qbuf = (u16*)(ws + XB + 4 * WT);
  u16* kbuf = (u16*)(ws + XB + 4 * WT + XB);
  u16* vtbuf= (u16*)(ws + XB + 4 * WT + 2 * XB);
  float* cost = (float*)(ws + XB + 4 * WT + 3 * XB);
  float* sint = cost + NS * 32;
  u64* maskbuf = (u64*)(ws + XB + 4 * WT + 3 * XB + (size_t)NS * 32 * 4 * 2);  // 1 MB
  u32* tilebits = (u32*)((char*)maskbuf + (size_t)NB * NS * 32 * 8);           // 256 B
  u16* attnout = xb;  // alias: xb is dead after the QKV GEMM (stream-ordered)

  prep_all<<<dim3(8448), 256, 0, stream>>>(Wq, Wk, Wv, Wo, WqT, WkT, WvT, WoT,
                                           x, xb, cost, sint);

  gemm_qkv<<<dim3(448), 512, 0, stream>>>(xb, WqT, bq, bk, bv, qbuf, kbuf, vtbuf, cost, sint,
                                          bar, inst, lidx, maskbuf, tilebits);

  attn_fused<<<dim3(1024), 256, 0, stream>>>(qbuf, kbuf, vtbuf, maskbuf, tilebits, attnout);

  gemm_out<<<dim3(256), 512, 0, stream>>>(attnout, WoT, bo, out);
}

// Round 26
// 109.568 us; speedup vs baseline: 1.0316x; 1.0316x over previous
//
#include <hip/hip_runtime.h>
#include <hip/hip_bf16.h>

typedef unsigned short u16;
typedef unsigned u32;
typedef unsigned long long u64;
typedef float f32x4 __attribute__((ext_vector_type(4)));
typedef __bf16 bf16x8 __attribute__((ext_vector_type(8)));

#define NB 2
#define NS 2048
#define ND 1024
#define NH 16
#define HD 64

__device__ inline u16 bfbits(float f) { __bf16 h = (__bf16)f; return __builtin_bit_cast(u16, h); }

__device__ inline void gl16(const u16* g, u16* l) {
  __builtin_amdgcn_global_load_lds((const __attribute__((address_space(1))) void*)(g),
                                   (__attribute__((address_space(3))) void*)(l), 16, 0, 0);
}

// ---------------- fused prep kernel (mask branch lives in gemm_qkv) ----------------
// blocks [0,4096): weight transpose f32->bf16^T (4 weights x 1024 tiles)
// blocks [4096,8192): x f32->bf16 convert
// blocks [8192,8448): rope tables
__global__ void __launch_bounds__(256)
prep_all(const float* __restrict__ W0, const float* __restrict__ W1,
         const float* __restrict__ W2, const float* __restrict__ W3,
         u16* __restrict__ T0, u16* __restrict__ T1, u16* __restrict__ T2, u16* __restrict__ T3,
         const float* __restrict__ x, u16* __restrict__ xb,
         float* __restrict__ cost, float* __restrict__ sint) {
  const int bid = blockIdx.x, t = threadIdx.x;
  if (bid < 4096) {
    __shared__ float tile[32][33];
    const float* Ws[4] = {W0, W1, W2, W3};
    u16* Ts[4] = {T0, T1, T2, T3};
    const float* __restrict__ W = Ws[bid >> 10];
    u16* __restrict__ WT = Ts[bid >> 10];
    const int rem = bid & 1023;
    const int n0 = (rem & 31) * 32, k0 = (rem >> 5) * 32;
    const int tx = t & 31, ty = t >> 5;
#pragma unroll
    for (int i = 0; i < 4; ++i)
      tile[ty + i * 8][tx] = W[(size_t)(k0 + ty + i * 8) * ND + n0 + tx];
    __syncthreads();
#pragma unroll
    for (int i = 0; i < 4; ++i)
      WT[(size_t)(n0 + ty + i * 8) * ND + k0 + tx] = bfbits(tile[tx][ty + i * 8]);
  } else if (bid < 8192) {
    const int i = (bid - 4096) * 256 + t;  // over NB*NS*ND/4
    float4 v = reinterpret_cast<const float4*>(x)[i];
    uint2 pk;
    pk.x = (unsigned)bfbits(v.x) | ((unsigned)bfbits(v.y) << 16);
    pk.y = (unsigned)bfbits(v.z) | ((unsigned)bfbits(v.w) << 16);
    reinterpret_cast<uint2*>(xb)[i] = pk;
  } else {
    const int i = (bid - 8192) * 256 + t;  // NS*32
    const int s = i >> 5, d = i & 31;
    float invf = powf(10000.f, -(float)d / 32.f);
    float a = (float)s * invf;
    cost[i] = cosf(a);
    sint[i] = sinf(a);
  }
}

// ---------------- fused QKV GEMM (v9: 256x256 BK=64 + closed-form mask tail) ----------------
// blocks [0,192): the v5 GEMM (1 block/CU, LDS 128KB, XOR-swizzled BK=64, wait-own vmcnt(0)
// -> s_barrier -> issue-next; 0 bank conflicts). blocks [192,256): closed-form mask builder.
// bar_ids SORTED per batch => for causal k<=q both FC rules pass only at off==0:
// vis(q,k) = G(k) | (qreal & bar[k]==bar[q]); same-bar set is a contiguous interval.
// Mask words are pure bit algebra (no ballot loop, no atomics). q pre-scaled by
// 0.125*log2(e); q/k stored in the HD-permuted packed-pair layout.
// [R25 post-mortem: 128x256/3-buffer variant regressed (B traffic doubled, intensity 128->85
// FLOP/byte); this 256^2 2-buffer config is the measured best at 48us.]
__global__ void __launch_bounds__(512, 2)
gemm_qkv(const u16* __restrict__ A, const u16* __restrict__ BT3,
         const float* __restrict__ bq, const float* __restrict__ bk, const float* __restrict__ bv,
         u16* __restrict__ qbuf, u16* __restrict__ kbuf, u16* __restrict__ vtbuf,
         const float* __restrict__ cost, const float* __restrict__ sint,
         const int* __restrict__ bar, const int* __restrict__ inst,
         const int* __restrict__ lidx, u64* __restrict__ mb, u32* __restrict__ tilebits) {
  constexpr int K = ND;
  __shared__ alignas(16) u16 Alds[2][256][64];  // 64 KB
  __shared__ alignas(16) u16 Blds[2][256][64];  // 64 KB
  const int t = threadIdx.x;
  const int hid = (int)blockIdx.x;              // 0..255

  if (hid >= 192) {
    // ---- closed-form mask tail ----
    int* sbar = reinterpret_cast<int*>(&Alds[0][0][0]);   // 16 KB
    int* sinst = sbar + NB * NS;                          // 16 KB
    int* firsts = reinterpret_cast<int*>(&Blds[0][0][0]); // NB*128 ints
    int* lasts = firsts + NB * 128;                       // NB*128 ints
    u64* Gw = reinterpret_cast<u64*>(lasts + NB * 128);   // NB*32 u64
    for (int i = t; i < NB * NS; i += 512) {
      sbar[i] = bar[i];
      sinst[i] = inst[i];
    }
    __syncthreads();
    for (int i = t; i < NB * NS; i += 512) {
      const int idx = i & (NS - 1);
      const int v = sbar[i];
      if (v >= 0 && v < 128) {
        if (idx == 0 || sbar[i - 1] != v) firsts[(i >> 11) * 128 + v] = idx;
        if (idx == NS - 1 || sbar[i + 1] != v) lasts[(i >> 11) * 128 + v] = idx;
      }
    }
    {
      const int w8 = t >> 6, lane = t & 63;
#pragma unroll
      for (int p8 = 0; p8 < 8; ++p8) {
        const int p = w8 * 8 + p8;
        const int gb = p >> 5, gkt = p & 31;
        const int k = gkt * 64 + lane;
        const bool gbit = (sinst[gb * NS + k] == 129) || (sbar[gb * NS + k] == -1);
        const u64 wd = __ballot(gbit);
        if (lane == 0) Gw[p] = wd;
      }
    }
    __syncthreads();
    const bool fc = (lidx[0] < 4);
    const int w8 = t >> 6, lane = t & 63;
    const int gw = (hid - 192) * 8 + w8;        // global wave id 0..511
#pragma unroll
    for (int rr = 0; rr < 8; ++rr) {
      const int pair = gw + 512 * rr;           // 0..4095 (strided: balanced)
      const int b = pair >> 11, q = pair & (NS - 1);
      const int qt = q >> 6;
      const int qb = sbar[b * NS + q];
      const bool qreal = sinst[b * NS + q] < 129;
      int lo = NS, hi = -1;
      if (fc && qreal && qb >= 0 && qb < 128) {
        lo = firsts[b * 128 + qb];
        hi = lasts[b * 128 + qb];
      }
      const int kt = lane;
      if (kt <= qt) {
        u64 word;
        if (!fc) {
          word = ~0ULL;
        } else {
          word = Gw[b * 32 + kt];
          const int base = kt * 64;
          const int s = lo - base, e = hi - base;
          if (e >= 0 && s <= 63) {
            const int cs = s < 0 ? 0 : s;
            const int ce = e > 63 ? 63 : e;
            u64 m = (ce >= 63) ? ~0ULL : ((1ULL << (ce + 1)) - 1);
            if (cs > 0) m &= ~((1ULL << cs) - 1);
            word |= m;
          }
        }
        if (kt == qt) {
          const int qq = q & 63;
          word &= (qq >= 63) ? ~0ULL : ((1ULL << (qq + 1)) - 1);
        }
        mb[(((size_t)b * NS + q) << 5) + kt] = word;
      }
    }
    if (hid == 192 && w8 == 0) {
      const int b = lane >> 5, qt = lane & 31;
      u32 tbw;
      if (!fc) {
        tbw = (qt >= 31) ? 0xFFFFFFFFu : ((1u << (qt + 1)) - 1);
      } else {
        const int v0 = sbar[b * NS + qt * 64];
        const int v1 = sbar[b * NS + qt * 64 + 63];
        const int lo_t = (v0 >= 0 && v0 < 128) ? firsts[b * 128 + v0] : 0;
        const int hi_t = (v1 >= 0 && v1 < 128) ? lasts[b * 128 + v1] : NS - 1;
        tbw = 0;
        for (int kt = 0; kt <= qt; ++kt) {
          const bool on = (kt == qt) || (Gw[b * 32 + kt] != 0ULL) ||
                          (kt * 64 <= hi_t && kt * 64 + 63 >= lo_t);
          if (on) tbw |= (1u << kt);
        }
      }
      if (lane < 64) tilebits[lane] = tbw;
    }
    return;
  }

  const int m0 = (hid / 12) << 8;               // 16 m-tiles of 256 rows
  const int nblk = hid % 12;
  const int proj = nblk >> 2;                   // 0:q 1:k 2:v
  const int n0 = (nblk & 3) << 8;               // within-proj col base (256-wide)
  const int w = t >> 6, lane = t & 63, lr = lane & 15, lg = lane >> 4;
  const int wm = w >> 2, wn = w & 3;            // 2 x 4 wave grid
  const float* __restrict__ bias = proj == 0 ? bq : (proj == 1 ? bk : bv);
  f32x4 acc[8][4] = {};

  const int srow = lane >> 3;  // 0..7
  const int lcol = (lane & 7) ^ srow;
  const u16* Ag = A + (size_t)(m0 + w * 32 + srow) * K + lcol * 8;
  const u16* Bg = BT3 + (size_t)(proj * ND + n0 + w * 32 + srow) * K + lcol * 8;
  const int swz = lr & 7;  // read-side XOR (row&7 == lr&7 for all fragment rows)

#pragma unroll
  for (int c = 0; c < 4; ++c) {
    gl16(Ag + (size_t)c * 8 * K, &Alds[0][w * 32 + c * 8][0]);
    gl16(Bg + (size_t)c * 8 * K, &Blds[0][w * 32 + c * 8][0]);
  }

  for (int s = 0; s < K / 64; ++s) {
    asm volatile("s_waitcnt vmcnt(0)" ::: "memory");  // own tile-s loads done
    __builtin_amdgcn_s_barrier();                     // all waves' loads done; buf[s^1] free
    if (s + 1 < K / 64) {
      const int k0n = (s + 1) * 64;
#pragma unroll
      for (int c = 0; c < 4; ++c) {
        gl16(Ag + k0n + (size_t)c * 8 * K, &Alds[(s + 1) & 1][w * 32 + c * 8][0]);
        gl16(Bg + k0n + (size_t)c * 8 * K, &Blds[(s + 1) & 1][w * 32 + c * 8][0]);
      }
    }
    const int cur = s & 1;
    bf16x8 bfr[4][2];
#pragma unroll
    for (int ni = 0; ni < 4; ++ni)
#pragma unroll
      for (int ks = 0; ks < 2; ++ks)
        bfr[ni][ks] = *reinterpret_cast<const bf16x8*>(
            &Blds[cur][wn * 64 + ni * 16 + lr][(((ks << 2) + lg) ^ swz) << 3]);
#pragma unroll
    for (int mi = 0; mi < 8; ++mi) {
#pragma unroll
      for (int ks = 0; ks < 2; ++ks) {
        const bf16x8 af = *reinterpret_cast<const bf16x8*>(
            &Alds[cur][wm * 128 + mi * 16 + lr][(((ks << 2) + lg) ^ swz) << 3]);
#pragma unroll
        for (int ni = 0; ni < 4; ++ni)
          acc[mi][ni] = __builtin_amdgcn_mfma_f32_16x16x32_bf16(af, bfr[ni][ks], acc[mi][ni], 0, 0, 0);
      }
    }
  }

  if (proj < 2) {
    u16* out = proj ? kbuf : qbuf;
    const float qs = proj == 0 ? 0.18033688f : 1.0f;  // 0.125 * log2(e): exp2-domain scores
    const int colbase = n0 + wn * 64;
    const int h = colbase >> 6;  // wave's 64 cols = one head
#pragma unroll
    for (int mi = 0; mi < 8; ++mi)
#pragma unroll
      for (int r = 0; r < 4; ++r) {
        const int row = m0 + wm * 128 + mi * 16 + lg * 4 + r;
        const int b = row >> 11, s = row & (NS - 1);
        u16* op = out + ((size_t)(b * NH + h) * NS + s) * HD;
#pragma unroll
        for (int nf = 0; nf < 2; ++nf) {
          const int dlo = nf * 16 + lr;  // < 32
          float lo = acc[mi][nf][r] + bias[colbase + dlo];
          float hi = acc[mi][nf + 2][r] + bias[colbase + dlo + 32];
          float c = cost[s * 32 + dlo], si = sint[s * 32 + dlo];
          const u32 pk = (u32)bfbits((lo * c - hi * si) * qs) |
                         ((u32)bfbits((hi * c + lo * si) * qs) << 16);
          *reinterpret_cast<u32*>(op + 2 * dlo) = pk;  // permuted layout: one 4B store
        }
      }
  } else {
    u16* out = vtbuf;
#pragma unroll
    for (int mi = 0; mi < 8; ++mi)
#pragma unroll
      for (int ni = 0; ni < 4; ++ni) {
        const int col = n0 + wn * 64 + ni * 16 + lr;
        const int h = col >> 6, d = col & 63;
        const int s0 = m0 + wm * 128 + mi * 16 + lg * 4;  // 4 consecutive s = r
        const int b = s0 >> 11, s = s0 & (NS - 1);
        uint2 pk;
        pk.x = (unsigned)bfbits(acc[mi][ni][0] + bias[col]) |
               ((unsigned)bfbits(acc[mi][ni][1] + bias[col]) << 16);
        pk.y = (unsigned)bfbits(acc[mi][ni][2] + bias[col]) |
               ((unsigned)bfbits(acc[mi][ni][3] + bias[col]) << 16);
        *reinterpret_cast<uint2*>(out + ((size_t)(b * NH + h) * HD + d) * NS + s) = pk;
      }
  }
}

// ---------------- output GEMM (v3: 128x128 tiles, BK=64, 3-buffer, 256 blocks) --------------
// C = A*B^T + bias, f32 out. 256 blocks x 512 threads = 1 block/CU. Tile 128x128, BK=64 with
// the XOR swizzle, 3-buffer LDS (96KB): wait-own vmcnt(4) -> s_barrier -> issue tile s+2.
// XCD map: each XCD owns one 128-col B panel (L2-resident) and walks the 32 m-tiles.
__global__ void __launch_bounds__(512)
gemm_out(const u16* __restrict__ A, const u16* __restrict__ BT, const float* __restrict__ bias,
         float* __restrict__ out) {
  constexpr int K = ND;
  __shared__ alignas(16) u16 Alds[3][128][64];  // 48 KB
  __shared__ alignas(16) u16 Blds[3][128][64];  // 48 KB
  const int t = threadIdx.x;
  const int hid = (int)blockIdx.x;              // 0..255
  const int n0 = (hid & 7) * 128;               // 8 n-tiles = 8 XCDs (B panel L2-resident)
  const int m0 = (hid >> 3) * 128;              // 32 m-tiles
  const int w = t >> 6, lane = t & 63, lr = lane & 15, lg = lane >> 4;
  const int wm = w >> 1, wn = w & 1;            // 4 x 2 wave grid
  f32x4 acc[2][4] = {};

  const int srow = lane >> 3;  // 0..7
  const int lcol = (lane & 7) ^ srow;
  const u16* Ag = A + (size_t)(m0 + w * 16 + srow) * K + lcol * 8;
  const u16* Bg = BT + (size_t)(n0 + w * 16 + srow) * K + lcol * 8;
  const int swz = lr & 7;

#pragma unroll
  for (int p = 0; p < 2; ++p) {
#pragma unroll
    for (int c = 0; c < 2; ++c) {
      gl16(Ag + p * 64 + (size_t)c * 8 * K, &Alds[p][w * 16 + c * 8][0]);
      gl16(Bg + p * 64 + (size_t)c * 8 * K, &Blds[p][w * 16 + c * 8][0]);
    }
  }

  int cur = 0;
  for (int s = 0; s < K / 64; ++s) {
    if (s + 1 < K / 64) {
      asm volatile("s_waitcnt vmcnt(4)" ::: "memory");
    } else {
      asm volatile("s_waitcnt vmcnt(0)" ::: "memory");
    }
    __builtin_amdgcn_s_barrier();
    if (s + 2 < K / 64) {
      int bn = cur + 2;
      if (bn >= 3) bn -= 3;
      const int k0n = (s + 2) * 64;
#pragma unroll
      for (int c = 0; c < 2; ++c) {
        gl16(Ag + k0n + (size_t)c * 8 * K, &Alds[bn][w * 16 + c * 8][0]);
        gl16(Bg + k0n + (size_t)c * 8 * K, &Blds[bn][w * 16 + c * 8][0]);
      }
    }
    bf16x8 bfr[4][2];
#pragma unroll
    for (int ni = 0; ni < 4; ++ni)
#pragma unroll
      for (int ks = 0; ks < 2; ++ks)
        bfr[ni][ks] = *reinterpret_cast<const bf16x8*>(
            &Blds[cur][wn * 64 + ni * 16 + lr][(((ks << 2) + lg) ^ swz) << 3]);
#pragma unroll
    for (int mi = 0; mi < 2; ++mi) {
#pragma unroll
      for (int ks = 0; ks < 2; ++ks) {
        const bf16x8 af = *reinterpret_cast<const bf16x8*>(
            &Alds[cur][wm * 32 + mi * 16 + lr][(((ks << 2) + lg) ^ swz) << 3]);
#pragma unroll
        for (int ni = 0; ni < 4; ++ni)
          acc[mi][ni] = __builtin_amdgcn_mfma_f32_16x16x32_bf16(af, bfr[ni][ks], acc[mi][ni], 0, 0, 0);
      }
    }
    cur = (cur == 2) ? 0 : cur + 1;
  }

#pragma unroll
  for (int mi = 0; mi < 2; ++mi)
#pragma unroll
    for (int r = 0; r < 4; ++r) {
      const int row = m0 + wm * 32 + mi * 16 + lg * 4 + r;
#pragma unroll
      for (int ni = 0; ni < 4; ++ni) {
        const int col = n0 + wn * 64 + ni * 16 + lr;
        out[(size_t)row * ND + col] = acc[mi][ni][r] + bias[col];
      }
    }
}

// ---------------- fused masked flash attention (v12: tilebits iteration) ----------
// grid 1024 x 4 waves, 64-row q-tiles, LDS 40KB -> 4 blocks/CU (16 waves). __syncthreads dbuf
// (race-free). Per-XCD mapping: xcd = hid&7 hosts 4 (b,h) panels; qt map {31-j, j, 23-j, 8+j}
// keeps the co-resident quad balanced. Iterate only set bits of tilebits[b*32+qt]; within a
// tile, waves whose 16 rows are all masked skip compute. q/k in HD-permuted layout
// (transparent here: Q and K share the permutation).
__global__ void __launch_bounds__(256, 4)
attn_fused(const u16* __restrict__ qb, const u16* __restrict__ kb, const u16* __restrict__ vtb,
           const u64* __restrict__ mb, const u32* __restrict__ tilebits,
           u16* __restrict__ attnout) {
  __shared__ alignas(16) u16 Klds[2][64][64];   // [buf][k][d]  rows 128B, swizzled 16B units
  __shared__ alignas(16) u16 Vlds[2][64][64];   // [buf][d][k]
  __shared__ alignas(16) u16 Plds[4][16][64];   // per-wave P [q][k], swizzled 8B units
  const int t = threadIdx.x, w = t >> 6, lane = t & 63, lr = lane & 15, lg = lane >> 4;
  const int hid = (int)blockIdx.x;              // 0..1023
  const int xcd = hid & 7, ix = hid >> 3;
  const int g = ix >> 5, r0 = ix & 31;
  const int bh = xcd * 4 + (r0 >> 3);
  const int b = bh >> 4, h = bh & 15;
  const int j = r0 & 7;
  const int qt = (g == 0) ? 31 - j : (g == 1) ? j : (g == 2) ? 23 - j : 8 + j;
  const int qbase = qt * 64;
  const u16* __restrict__ qh = qb + (size_t)(b * NH + h) * NS * HD;
  const u16* __restrict__ kh = kb + (size_t)(b * NH + h) * NS * HD;
  const u16* __restrict__ vth = vtb + (size_t)(b * NH + h) * HD * NS;
  const u32 bits = tilebits[b * 32 + qt];       // nonzero: diagonal always visible
  const int nt = __popc(bits);

  const int srow = lane >> 3;  // 0..7
  const int lcol = (lane & 7) ^ srow;
  const int sw = lr & 7;

  const int qrow = qbase + w * 16 + lr;
  const bf16x8 qf0 = *reinterpret_cast<const bf16x8*>(qh + (size_t)qrow * HD + lg * 8);
  const bf16x8 qf1 = *reinterpret_cast<const bf16x8*>(qh + (size_t)qrow * HD + 32 + lg * 8);
  const u64* __restrict__ mrow = mb + (((size_t)b * NS + qrow) << 5);

  float m_s = -1e30f, l_s = 0.f;
  f32x4 oacc[4] = {};
  int cur = 0;

  const int kt0 = __ffs(bits) - 1;
  u32 rem = bits & (bits - 1);
  {
    const int kb0 = kt0 << 6;
#pragma unroll
    for (int c = 0; c < 2; ++c) {
      const int row = w * 16 + c * 8 + srow;
      gl16(kh + (size_t)(kb0 + row) * HD + lcol * 8, &Klds[0][w * 16 + c * 8][0]);
      gl16(vth + (size_t)row * NS + kb0 + lcol * 8, &Vlds[0][w * 16 + c * 8][0]);
    }
  }
  u64 mw = mrow[kt0];

  for (int i = 0; i < nt; ++i) {
    __syncthreads();  // drains vmcnt: buf[cur] staged by ALL waves; buf[cur^1] free
    u64 mwn = 0ULL;
    if (rem) {
      const int ktn = __ffs(rem) - 1;
      rem &= rem - 1;
      const int kb0n = ktn << 6;
#pragma unroll
      for (int c = 0; c < 2; ++c) {
        const int row = w * 16 + c * 8 + srow;
        gl16(kh + (size_t)(kb0n + row) * HD + lcol * 8, &Klds[cur ^ 1][w * 16 + c * 8][0]);
        gl16(vth + (size_t)row * NS + kb0n + lcol * 8, &Vlds[cur ^ 1][w * 16 + c * 8][0]);
      }
      mwn = mrow[ktn];
    }

    if (!__all(mw == 0ULL)) {
      const u16* Kb = &Klds[cur][0][0];
      const u16* Vb = &Vlds[cur][0][0];

      f32x4 sacc[4] = {};
      __builtin_amdgcn_s_setprio(1);
#pragma unroll
      for (int n = 0; n < 4; ++n) {
        const u16* kr = Kb + (n * 16 + lr) * 64;
        bf16x8 kf0 = *reinterpret_cast<const bf16x8*>(kr + ((lg ^ sw) << 3));
        bf16x8 kf1 = *reinterpret_cast<const bf16x8*>(kr + (((4 + lg) ^ sw) << 3));
        sacc[n] = __builtin_amdgcn_mfma_f32_16x16x32_bf16(kf0, qf0, sacc[n], 0, 0, 0);
        sacc[n] = __builtin_amdgcn_mfma_f32_16x16x32_bf16(kf1, qf1, sacc[n], 0, 0, 0);
      }
      __builtin_amdgcn_s_setprio(0);

      float pm[4][4];
      float mx4[4];
#pragma unroll
      for (int n = 0; n < 4; ++n) {
#pragma unroll
        for (int r = 0; r < 4; ++r) {
          const bool vis = (mw >> (n * 16 + lg * 4 + r)) & 1ULL;
          pm[n][r] = vis ? sacc[n][r] : -3e30f;
        }
        mx4[n] = fmaxf(fmaxf(pm[n][0], pm[n][1]), fmaxf(pm[n][2], pm[n][3]));
      }
      float mx = fmaxf(fmaxf(mx4[0], mx4[1]), fmaxf(mx4[2], mx4[3]));
      mx = fmaxf(mx, __shfl_xor(mx, 16));
      mx = fmaxf(mx, __shfl_xor(mx, 32));

      const bool skip = __all(mx <= m_s + 11.5415603f);
      const float mn = skip ? m_s : fmaxf(m_s, mx);

      float rs = 0.f;
#pragma unroll
      for (int n = 0; n < 4; ++n) {
        const float e0 = exp2f(pm[n][0] - mn);
        const float e1 = exp2f(pm[n][1] - mn);
        const float e2 = exp2f(pm[n][2] - mn);
        const float e3 = exp2f(pm[n][3] - mn);
        rs += (e0 + e1) + (e2 + e3);
        uint2 pk;
        pk.x = (unsigned)bfbits(e0) | ((unsigned)bfbits(e1) << 16);
        pk.y = (unsigned)bfbits(e2) | ((unsigned)bfbits(e3) << 16);
        *reinterpret_cast<uint2*>(&Plds[w][lr][(((n << 2) + lg) ^ (lr & 14)) << 2]) = pk;
      }
      rs += __shfl_xor(rs, 16);
      rs += __shfl_xor(rs, 32);

      if (skip) {
        l_s += rs;
      } else {
        const float sf = exp2f(m_s - mn);
        m_s = mn;
        l_s = l_s * sf + rs;
        float sfr[4];
#pragma unroll
        for (int r = 0; r < 4; ++r) sfr[r] = __shfl(sf, lg * 4 + r);
#pragma unroll
        for (int nd = 0; nd < 4; ++nd)
#pragma unroll
          for (int r = 0; r < 4; ++r) oacc[nd][r] *= sfr[r];
      }

      const bf16x8 pf0 = *reinterpret_cast<const bf16x8*>(&Plds[w][lr][((2 * lg) ^ (lr & 14)) << 2]);
      const bf16x8 pf1 = *reinterpret_cast<const bf16x8*>(&Plds[w][lr][((8 + 2 * lg) ^ (lr & 14)) << 2]);
      __builtin_amdgcn_s_setprio(1);
#pragma unroll
      for (int nd = 0; nd < 4; ++nd) {
        const u16* vr = Vb + (nd * 16 + lr) * 64;
        bf16x8 vf0 = *reinterpret_cast<const bf16x8*>(vr + ((lg ^ sw) << 3));
        bf16x8 vf1 = *reinterpret_cast<const bf16x8*>(vr + (((4 + lg) ^ sw) << 3));
        oacc[nd] = __builtin_amdgcn_mfma_f32_16x16x32_bf16(pf0, vf0, oacc[nd], 0, 0, 0);
        oacc[nd] = __builtin_amdgcn_mfma_f32_16x16x32_bf16(pf1, vf1, oacc[nd], 0, 0, 0);
      }
      __builtin_amdgcn_s_setprio(0);
    }

    mw = mwn;
    cur ^= 1;
  }

  float il[4];
#pragma unroll
  for (int r = 0; r < 4; ++r) il[r] = 1.f / __shfl(l_s, lg * 4 + r);
#pragma unroll
  for (int nd = 0; nd < 4; ++nd)
#pragma unroll
    for (int r = 0; r < 4; ++r) {
      const int i = qbase + w * 16 + lg * 4 + r;
      attnout[(size_t)(b * NS + i) * ND + h * HD + nd * 16 + lr] = bfbits(oacc[nd][r] * il[r]);
    }
}

// ---------------- launch ----------------
extern "C" void kernel_launch(void* const* d_in, const int* in_sizes, int n_in,
                              void* d_out, int out_size, void* d_ws, size_t ws_size,
                              hipStream_t stream) {
  const float* x = (const float*)d_in[0];
  const int* bar = (const int*)d_in[1];
  const int* inst = (const int*)d_in[2];
  const int* lidx = (const int*)d_in[3];
  const float* Wq = (const float*)d_in[4];
  const float* bq = (const float*)d_in[5];
  const float* Wk = (const float*)d_in[6];
  const float* bk = (const float*)d_in[7];
  const float* Wv = (const float*)d_in[8];
  const float* bv = (const float*)d_in[9];
  const float* Wo = (const float*)d_in[10];
  const float* bo = (const float*)d_in[11];
  float* out = (float*)d_out;

  char* ws = (char*)d_ws;
  constexpr size_t XB = (size_t)NB * NS * ND * 2;   // 8 MB bf16 token-major buffer
  constexpr size_t WT = (size_t)ND * ND * 2;        // 2 MB
  u16* xb   = (u16*)(ws);
  u16* WqT  = (u16*)(ws + XB);                      // WqT|WkT|WvT contiguous = [3072][1024]
  u16* WkT  = (u16*)(ws + XB + 1 * WT);
  u16* WvT  = (u16*)(ws + XB + 2 * WT);
  u16* WoT  = (u16*)(ws + XB + 3 * WT);
  u16* qbuf = (u16*)(ws + XB + 4 * WT);
  u16* kbuf = (u16*)(ws + XB + 4 * WT + XB);
  u16* vtbuf= (u16*)(ws + XB + 4 * WT + 2 * XB);
  float* cost = (float*)(ws + XB + 4 * WT + 3 * XB);
  float* sint = cost + NS * 32;
  u64* maskbuf = (u64*)(ws + XB + 4 * WT + 3 * XB + (size_t)NS * 32 * 4 * 2);  // 1 MB
  u32* tilebits = (u32*)((char*)maskbuf + (size_t)NB * NS * 32 * 8);           // 256 B
  u16* attnout = xb;  // alias: xb is dead after the QKV GEMM (stream-ordered)

  prep_all<<<dim3(8448), 256, 0, stream>>>(Wq, Wk, Wv, Wo, WqT, WkT, WvT, WoT,
                                           x, xb, cost, sint);

  gemm_qkv<<<dim3(256), 512, 0, stream>>>(xb, WqT, bq, bk, bv, qbuf, kbuf, vtbuf, cost, sint,
                                          bar, inst, lidx, maskbuf, tilebits);

  attn_fused<<<dim3(1024), 256, 0, stream>>>(qbuf, kbuf, vtbuf, maskbuf, tilebits, attnout);

  gemm_out<<<dim3(256), 512, 0, stream>>>(attnout, WoT, bo, out);
}